// Round 3
// baseline (16663.765 us; speedup 1.0000x reference)
//
#include <hip/hip_runtime.h>
#include <cstddef>
#include <cstdint>

// GRU B=64 T=1024 I=H=512.  Design:
//  prep: fp32->bf16 fragment-ordered weights (6 matrices) + zero tag regions
//  proj: xr/xz/xn = x @ W_i*^T  (bf16 MFMA, output bf16 slabs [T][B][H])
//  scan: persistent 32-WG kernel, j-split (16 cols/WG), LDS-resident weight
//        slices, M=64 MFMA, fragment-ordered h / r*h exchange through L2/L3.
//  v2: distributed per-WG flag barrier, x[t+1] register prefetch +
//      double-buffered xstage, out-stores/LDS x-writes in barrier shadow.
//  v3: relaxed AGENT-scope data publish (sc1, no wbl2/inv) + relaxed flags.
//  v4: SELF-VALIDATING TAGGED FRAMES - no flags at all.  Every exchanged
//      dword = (bf16 payload << 16) | seq_tag.  Stored as relaxed agent
//      qword atomics (8B natively atomic -> low-dword tag validates qword).
//      Consumers poll the data itself and retry until all tags match the
//      expected sequence (h: 2t+1, r*h: 2t+2).  This removes the producer
//      retire-wait leg AND the flag-propagation leg: one coherence RT per
//      phase instead of three.  Monotonic tags + progress-certifies-reads
//      make in-place overwrite race-free and deadlock-free.

#define NWG 32

typedef __attribute__((ext_vector_type(8))) short bf16x8;
typedef __attribute__((ext_vector_type(4))) float f32x4;

__device__ inline unsigned short f2bf(float f) {
  unsigned int u = __float_as_uint(f);
  unsigned int r = (u + 0x7fffu + ((u >> 16) & 1u)) >> 16;
  return (unsigned short)r;
}
__device__ inline float bf2f(unsigned short s) {
  return __uint_as_float(((unsigned int)s) << 16);
}
__device__ inline bf16x8 as_bf(uint4 v) {
  union { uint4 u; bf16x8 b; } x; x.u = v; return x.b;
}
__device__ inline float sigm(float x) {
  x = fminf(fmaxf(x, -30.f), 30.f);
  return 1.f / (1.f + __expf(-x));
}
__device__ inline float tanhfast(float x) {
  x = fminf(fmaxf(x, -15.f), 15.f);
  float e = __expf(-2.f * x);
  return (1.f - e) / (1.f + e);
}

// ---- tagged-frame helpers -------------------------------------------------
// Tagged chunk: 8 payload bf16 -> 8 dwords [payload<<16 | tag] -> 4 qwords.
// One producer thread owns one chunk (4 qword atomic stores); one consumer
// (lane,kt) reads exactly that chunk back (4 qword atomic loads).
__device__ inline void pubtag(unsigned long long* qbase, uint4 u, unsigned tg) {
  unsigned wl[4] = {u.x, u.y, u.z, u.w};
#pragma unroll
  for (int j = 0; j < 4; ++j) {
    unsigned wv = wl[j];
    unsigned long long q =
        ((unsigned long long)((wv & 0xffff0000u) | tg) << 32) |
        (unsigned long long)((wv << 16) | tg);
    __hip_atomic_store(qbase + j, q, __ATOMIC_RELAXED, __HIP_MEMORY_SCOPE_AGENT);
  }
}
// repack one qword (2 tagged dwords) into one packed dword (2 bf16)
__device__ inline unsigned pk2(unsigned long long q) {
  return (((unsigned)(q >> 16)) & 0xffffu) | (((unsigned)(q >> 32)) & 0xffff0000u);
}
// poll-read a full A-fragment set (16 kt x 4 qwords) until every qword's tag
// matches tg; masked-out (done) lanes keep their af values across retries.
__device__ inline void pollread(const unsigned long long* qarr, int w, int lane,
                                unsigned tg, uint4* af) {
  unsigned ok;
  do {
    ok = 1u;
#pragma unroll
    for (int kt = 0; kt < 16; ++kt) {
      const unsigned long long* qb = qarr + ((size_t)(w * 16 + kt) * 64 + lane) * 4;
      unsigned long long q0 = __hip_atomic_load(qb + 0, __ATOMIC_RELAXED, __HIP_MEMORY_SCOPE_AGENT);
      unsigned long long q1 = __hip_atomic_load(qb + 1, __ATOMIC_RELAXED, __HIP_MEMORY_SCOPE_AGENT);
      unsigned long long q2 = __hip_atomic_load(qb + 2, __ATOMIC_RELAXED, __HIP_MEMORY_SCOPE_AGENT);
      unsigned long long q3 = __hip_atomic_load(qb + 3, __ATOMIC_RELAXED, __HIP_MEMORY_SCOPE_AGENT);
      ok &= (unsigned)((((unsigned)q0) & 0xffffu) == tg);
      ok &= (unsigned)((((unsigned)q1) & 0xffffu) == tg);
      ok &= (unsigned)((((unsigned)q2) & 0xffffu) == tg);
      ok &= (unsigned)((((unsigned)q3) & 0xffffu) == tg);
      af[kt].x = pk2(q0); af[kt].y = pk2(q1);
      af[kt].z = pk2(q2); af[kt].w = pk2(q3);
    }
  } while (!ok);
}

// ---------------------------------------------------------------- prep
// wfrag layout per gate (262144 ushorts): idx = ((jt*16+kt)*64+lane)*8+i
// holds W[j=jt*16+(lane&15)][k=kt*32+(lane>>4)*8+i]  (MFMA B-fragment order)
// Also zeroes bar (unused legacy) + the two tagged frag arrays (tag 0).
__global__ void prep_kernel(const float* Wir, const float* Wiz, const float* Win,
                            const float* Whr, const float* Whz, const float* Whn,
                            unsigned short* wfrag, int* bar, int* zfr) {
  const float* Ws[6] = {Wir, Wiz, Win, Whr, Whz, Whn};
  int idx = blockIdx.x * 256 + threadIdx.x;
  if (idx < 6 * 262144) {
    int g = idx >> 18;
    int r = idx & 262143;
    int i = r & 7, lane = (r >> 3) & 63, kt = (r >> 9) & 15, jt = r >> 13;
    int n = lane & 15, q = lane >> 4;
    int j = jt * 16 + n, k = kt * 32 + q * 8 + i;
    wfrag[idx] = f2bf(Ws[g][j * 512 + k]);
  } else {
    int z = idx - 6 * 262144;
    if (z < 4096) bar[z] = 0;
    else if (z < 69632) zfr[z - 4096] = 0;   // hfragT + rhfragT (256 KB)
  }
}

// ---------------------------------------------------------------- proj
// grid 8192: XCD-swizzled so the 8 j-tiles of one m-tile share an XCD (L2 reuse
// of the x A-tile).  Per WG: 64 (b,t)-rows x 64 j, K=512, 3 gates reuse A.
__global__ __launch_bounds__(256) void proj_kernel(const float* __restrict__ x,
                                                   const unsigned short* __restrict__ wfrag,
                                                   unsigned short* __restrict__ xslab) {
  __shared__ __align__(16) unsigned short As[64 * 520];
  int bid = blockIdx.x;
  int mLow = bid & 7, j8 = (bid >> 3) & 7, mHigh = bid >> 6;
  int mt = mHigh * 8 + mLow;            // 0..1023  (64-row tile of flattened b*T+t)
  int j0 = j8 * 64;
  int bb = mt >> 4, t0 = (mt & 15) << 6; // tile stays within one batch (T%64==0)
  const float* xbase = x + ((size_t)bb * 1024 + t0) * 512;
  for (int c = threadIdx.x; c < 64 * 128; c += 256) {
    int row = c >> 7, f4 = c & 127;
    float4 v = *((const float4*)(xbase + row * 512 + f4 * 4));
    ushort4 o;
    o.x = f2bf(v.x); o.y = f2bf(v.y); o.z = f2bf(v.z); o.w = f2bf(v.w);
    *((ushort4*)(As + row * 520 + f4 * 4)) = o;
  }
  __syncthreads();
  int lane = threadIdx.x & 63, w = threadIdx.x >> 6;
  int nn = lane & 15, qq = lane >> 4;
  for (int gate = 0; gate < 3; ++gate) {
    const unsigned short* wb = wfrag + (size_t)gate * 262144;
    f32x4 acc0 = {0.f,0.f,0.f,0.f}, acc1 = {0.f,0.f,0.f,0.f};
    f32x4 acc2 = {0.f,0.f,0.f,0.f}, acc3 = {0.f,0.f,0.f,0.f};
#pragma unroll
    for (int kt = 0; kt < 16; ++kt) {
      bf16x8 a = *((const bf16x8*)(As + (w * 16 + nn) * 520 + kt * 32 + qq * 8));
      uint4 b0 = *((const uint4*)(wb + (((size_t)(j8 * 4 + 0) * 16 + kt) * 64 + lane) * 8));
      uint4 b1 = *((const uint4*)(wb + (((size_t)(j8 * 4 + 1) * 16 + kt) * 64 + lane) * 8));
      uint4 b2 = *((const uint4*)(wb + (((size_t)(j8 * 4 + 2) * 16 + kt) * 64 + lane) * 8));
      uint4 b3 = *((const uint4*)(wb + (((size_t)(j8 * 4 + 3) * 16 + kt) * 64 + lane) * 8));
      acc0 = __builtin_amdgcn_mfma_f32_16x16x32_bf16(a, as_bf(b0), acc0, 0, 0, 0);
      acc1 = __builtin_amdgcn_mfma_f32_16x16x32_bf16(a, as_bf(b1), acc1, 0, 0, 0);
      acc2 = __builtin_amdgcn_mfma_f32_16x16x32_bf16(a, as_bf(b2), acc2, 0, 0, 0);
      acc3 = __builtin_amdgcn_mfma_f32_16x16x32_bf16(a, as_bf(b3), acc3, 0, 0, 0);
    }
    unsigned short* outs = xslab + (size_t)gate * 33554432;
    f32x4 accs[4] = {acc0, acc1, acc2, acc3};
#pragma unroll
    for (int jt = 0; jt < 4; ++jt) {
#pragma unroll
      for (int r = 0; r < 4; ++r) {
        int t = t0 + w * 16 + qq * 4 + r;
        int j = j0 + jt * 16 + nn;
        outs[(size_t)t * 32768 + bb * 512 + j] = f2bf(accs[jt][r]);
      }
    }
  }
}

// ---------------------------------------------------------------- scan
// WG g owns j in [g*16, g*16+16).  hfragT/rhfragT (tagged, dwords):
// [mt(4)][kt(16)][lane(64)][8 dwords], dword = payload<<16 | tag.
// Tags: h for step t carries 2t+1 (h0 init = 1), r*h at step t carries 2t+2.
__global__ __launch_bounds__(256) void scan_kernel(
    const unsigned short* __restrict__ wfragH, const unsigned short* __restrict__ xslab,
    const float* __restrict__ h0, const float* __restrict__ bhr,
    const float* __restrict__ bhz, const float* __restrict__ bhn,
    float* __restrict__ out, unsigned long long* hfragT, unsigned long long* rhfragT) {
  __shared__ __align__(16) unsigned short whf[3 * 8192];          // 48 KB weight slices
  __shared__ __align__(16) unsigned short xstage[2][3 * 64 * 16]; // double-buffered x
  __shared__ float hloc[64 * 17];
  __shared__ __align__(16) unsigned short rhst[64 * 16];
  __shared__ __align__(16) unsigned short hst[64 * 16];
  const int g = blockIdx.x, tid = threadIdx.x;
  const int lane = tid & 63, w = tid >> 6;
  const int nn = lane & 15, qq = lane >> 4;

  // x-prefetch addressing: task tid, plus task 256+tid for tid<128
  const int gate0 = tid >> 7, sub0 = tid & 127, xb0 = sub0 >> 1, xh0 = sub0 & 1;
  const size_t xg0 = (size_t)gate0 * 33554432 + xb0 * 512 + g * 16 + xh0 * 8;
  const int xl0 = (gate0 * 64 + xb0) * 16 + xh0 * 8;
  const int xb1 = tid >> 1, xh1 = tid & 1;   // gate 2, tid<128 only
  const size_t xg1 = (size_t)2 * 33554432 + xb1 * 512 + g * 16 + xh1 * 8;
  const int xl1 = (2 * 64 + xb1) * 16 + xh1 * 8;
  uint4 xpf0 = {0,0,0,0}, xpf1 = {0,0,0,0};

  // publish addressing (tid<128): chunk (b,q) -> frag[mt][g>>1][lg], 4 qwords
  const int pb = tid >> 1, pq = tid & 1;
  const int pmt = pb >> 4, pktg = g >> 1, pqg = ((g & 1) << 1) | pq;
  const int plg = (pb & 15) | (pqg << 4);
  const size_t pqoff = ((size_t)(pmt * 16 + pktg) * 64 + plg) * 4;

  // weight slices: jt == g is a contiguous 8192-ushort run per gate
  for (int c = tid; c < 3 * 1024; c += 256) {
    int gate = c >> 10, chunk = c & 1023;
    *((uint4*)(whf + gate * 8192 + chunk * 8)) =
        *((const uint4*)(wfragH + (size_t)gate * 262144 + (size_t)g * 8192 + chunk * 8));
  }
  // local fp32 h slice
  {
    int b = tid >> 2, c = tid & 3;
    float4 v = *((const float4*)(h0 + b * 512 + g * 16 + c * 4));
    hloc[b * 17 + c * 4 + 0] = v.x; hloc[b * 17 + c * 4 + 1] = v.y;
    hloc[b * 17 + c * 4 + 2] = v.z; hloc[b * 17 + c * 4 + 3] = v.w;
  }
  // init this WG's k-slice of hfrag from h_0, tag 1 (= 2*0+1)
  if (tid < 128) {
    int k0 = g * 16 + pq * 8;
    float4 v0 = *((const float4*)(h0 + pb * 512 + k0));
    float4 v1 = *((const float4*)(h0 + pb * 512 + k0 + 4));
    union { unsigned short s[8]; uint4 v; } u;
    u.s[0] = f2bf(v0.x); u.s[1] = f2bf(v0.y); u.s[2] = f2bf(v0.z); u.s[3] = f2bf(v0.w);
    u.s[4] = f2bf(v1.x); u.s[5] = f2bf(v1.y); u.s[6] = f2bf(v1.z); u.s[7] = f2bf(v1.w);
    pubtag(hfragT + pqoff, u.v, 1u);
  }
  // stage x[t=0]
  xpf0 = *((const uint4*)(xslab + xg0));
  if (tid < 128) xpf1 = *((const uint4*)(xslab + xg1));
  *((uint4*)(&xstage[0][xl0])) = xpf0;
  if (tid < 128) *((uint4*)(&xstage[0][xl1])) = xpf1;

  const float br = bhr[g * 16 + nn], bz = bhz[g * 16 + nn], bn = bhn[g * 16 + nn];
  __syncthreads();   // whf / hloc / xstage[0] ready

  for (int t = 0; t < 1024; ++t) {
    const unsigned short* xs = xstage[t & 1];
    // issue x[t+1] global loads now; consumed in the end-of-step shadow
    if (t < 1023) {
      xpf0 = *((const uint4*)(xslab + (size_t)(t + 1) * 32768 + xg0));
      if (tid < 128) xpf1 = *((const uint4*)(xslab + (size_t)(t + 1) * 32768 + xg1));
    }

    // ---- phase 1: poll h (tag 2t+1), compute r,z, publish r*h (tag 2t+2)
    uint4 af[16];
    pollread(hfragT, w, lane, (unsigned)(2 * t + 1), af);
    __syncthreads();   // also guards xstage[t&1] writes from step t-1
    f32x4 ar = {0.f,0.f,0.f,0.f}, az = {0.f,0.f,0.f,0.f};
#pragma unroll
    for (int kt = 0; kt < 16; ++kt) {
      bf16x8 a = as_bf(af[kt]);
      bf16x8 b0 = *((const bf16x8*)(whf + 0 * 8192 + (kt * 64 + lane) * 8));
      bf16x8 b1 = *((const bf16x8*)(whf + 1 * 8192 + (kt * 64 + lane) * 8));
      ar = __builtin_amdgcn_mfma_f32_16x16x32_bf16(a, b0, ar, 0, 0, 0);
      az = __builtin_amdgcn_mfma_f32_16x16x32_bf16(a, b1, az, 0, 0, 0);
    }
    float zv[4];
#pragma unroll
    for (int r = 0; r < 4; ++r) {
      int b = w * 16 + qq * 4 + r;
      float xr = bf2f(xs[(0 * 64 + b) * 16 + nn]);
      float xz = bf2f(xs[(1 * 64 + b) * 16 + nn]);
      float rv = sigm(ar[r] + xr + br);
      zv[r] = sigm(az[r] + xz + bz);
      rhst[b * 16 + nn] = f2bf(rv * hloc[b * 17 + nn]);
    }
    __syncthreads();
    if (tid < 128)
      pubtag(rhfragT + pqoff, *((const uint4*)(rhst + pb * 16 + pq * 8)),
             (unsigned)(2 * t + 2));

    // ---- phase 2: poll r*h (tag 2t+2), compute n + h, publish h (tag 2t+3)
    pollread(rhfragT, w, lane, (unsigned)(2 * t + 2), af);
    f32x4 an = {0.f,0.f,0.f,0.f};
#pragma unroll
    for (int kt = 0; kt < 16; ++kt) {
      bf16x8 a = as_bf(af[kt]);
      bf16x8 b2 = *((const bf16x8*)(whf + 2 * 8192 + (kt * 64 + lane) * 8));
      an = __builtin_amdgcn_mfma_f32_16x16x32_bf16(a, b2, an, 0, 0, 0);
    }
    float hv[4];
#pragma unroll
    for (int r = 0; r < 4; ++r) {
      int b = w * 16 + qq * 4 + r;
      float xn = bf2f(xs[(2 * 64 + b) * 16 + nn]);
      float nv = tanhfast(an[r] + xn + bn);
      float ho = hloc[b * 17 + nn];
      float hn = (1.f - zv[r]) * ho + zv[r] * nv;
      hloc[b * 17 + nn] = hn;
      hv[r] = hn;
      hst[b * 16 + nn] = f2bf(hn);
    }
    __syncthreads();
    if (tid < 128)
      pubtag(hfragT + pqoff, *((const uint4*)(hst + pb * 16 + pq * 8)),
             (unsigned)(2 * t + 3));
    // ---- publish shadow: HBM out-stores + next-step LDS x-write
#pragma unroll
    for (int r = 0; r < 4; ++r) {
      int b = w * 16 + qq * 4 + r;
      out[((size_t)b * 1024 + t) * 512 + g * 16 + nn] = hv[r];
      if (t == 1023) out[(size_t)33554432 + b * 512 + g * 16 + nn] = hv[r];
    }
    if (t < 1023) {
      unsigned short* xw = xstage[(t + 1) & 1];
      *((uint4*)(&xw[xl0])) = xpf0;
      if (tid < 128) *((uint4*)(&xw[xl1])) = xpf1;
    }
  }
}

// ---------------------------------------------------------------- launch
extern "C" void kernel_launch(void* const* d_in, const int* in_sizes, int n_in,
                              void* d_out, int out_size, void* d_ws, size_t ws_size,
                              hipStream_t stream) {
  (void)in_sizes; (void)n_in; (void)out_size; (void)ws_size;
  const float* x   = (const float*)d_in[0];
  const float* h0  = (const float*)d_in[1];
  const float* Wir = (const float*)d_in[2];
  const float* Wiz = (const float*)d_in[3];
  const float* Win = (const float*)d_in[4];
  const float* Whr = (const float*)d_in[5];
  const float* Whz = (const float*)d_in[6];
  const float* Whn = (const float*)d_in[7];
  const float* bhr = (const float*)d_in[8];
  const float* bhz = (const float*)d_in[9];
  const float* bhn = (const float*)d_in[10];
  float* out = (float*)d_out;
  char* w = (char*)d_ws;
  // ws layout (bytes):
  //   wfrag   @ 0           : 6*262144*2 = 3,145,728
  //   xslab   @ 3,145,728   : 3*33,554,432*2 = 201,326,592
  //   hfragT  @ 204,472,320 : 131,072   (tagged, 2x payload)
  //   rhfragT @ 204,603,392 : 131,072
  //   bar     @ 204,734,464 : 16,384    (legacy, zeroed, unused)
  unsigned short* wfrag = (unsigned short*)w;
  unsigned short* xslab = (unsigned short*)(w + 3145728);
  unsigned long long* hfragT  = (unsigned long long*)(w + 204472320);
  unsigned long long* rhfragT = (unsigned long long*)(w + 204603392);
  int* bar = (int*)(w + 204734464);
  int* zfr = (int*)(w + 204472320);   // zero both tagged arrays (65536 ints)

  hipLaunchKernelGGL(prep_kernel, dim3(6416), dim3(256), 0, stream,
                     Wir, Wiz, Win, Whr, Whz, Whn, wfrag, bar, zfr);
  hipLaunchKernelGGL(proj_kernel, dim3(8192), dim3(256), 0, stream,
                     x, wfrag, xslab);
  hipLaunchKernelGGL(scan_kernel, dim3(NWG), dim3(256), 0, stream,
                     wfrag + (size_t)3 * 262144, xslab, h0, bhr, bhz, bhn,
                     out, hfragT, rhfragT);
}

// Round 4
// 7296.917 us; speedup vs baseline: 2.2837x; 2.2837x over previous
//
#include <hip/hip_runtime.h>
#include <cstddef>
#include <cstdint>

// GRU B=64 T=1024 I=H=512.  Design:
//  prep: fp32->bf16 fragment-ordered weights (6 matrices) + zero barrier flags
//  proj: xr/xz/xn = x @ W_i*^T  (bf16 MFMA, output bf16 slabs [T][B][H])
//  scan: persistent 32-WG kernel, j-split (16 cols/WG), LDS-resident weight
//        slices, M=64 MFMA, fragment-ordered h / r*h exchange through L2/L3.
//  v3: relaxed AGENT-scope data publish (sc1, no wbl2/inv) + relaxed flags.
//  v5: WAVE-AUTONOMOUS planes - zero __syncthreads in the steady loop.
//      Consumer wave w only reads frag rows mt==w, produced only by waves
//      with the same w across WGs -> 4 independent 32-wave planes.
//      Per-wave flags (128 lines x2 sets), per-wave publish via private
//      512B LDS staging + intra-wave lgkmcnt fence, per-wave vmcnt(0)
//      drain (own stores only) before the flag store.  x lives in 12
//      scalar ushort regs loaded in the flag shadow (no xstage LDS);
//      h state lives in 4 regs (hreg).  Out-stores in poll shadow.

#define NWG 32

typedef __attribute__((ext_vector_type(8))) short bf16x8;
typedef __attribute__((ext_vector_type(4))) float f32x4;

__device__ inline unsigned short f2bf(float f) {
  unsigned int u = __float_as_uint(f);
  unsigned int r = (u + 0x7fffu + ((u >> 16) & 1u)) >> 16;
  return (unsigned short)r;
}
__device__ inline float bf2f(unsigned short s) {
  return __uint_as_float(((unsigned int)s) << 16);
}
__device__ inline bf16x8 as_bf(uint4 v) {
  union { uint4 u; bf16x8 b; } x; x.u = v; return x.b;
}
__device__ inline float sigm(float x) {
  x = fminf(fmaxf(x, -30.f), 30.f);
  return 1.f / (1.f + __expf(-x));
}
__device__ inline float tanhfast(float x) {
  x = fminf(fmaxf(x, -15.f), 15.f);
  float e = __expf(-2.f * x);
  return (1.f - e) / (1.f + e);
}

// Device-coherent 16B publish/read (2x qword relaxed AGENT atomics -> sc1).
__device__ inline void pub16(unsigned short* dst, uint4 v) {
  union { uint4 u; unsigned long long q[2]; } x; x.u = v;
  unsigned long long* d = (unsigned long long*)dst;
  __hip_atomic_store(d + 0, x.q[0], __ATOMIC_RELAXED, __HIP_MEMORY_SCOPE_AGENT);
  __hip_atomic_store(d + 1, x.q[1], __ATOMIC_RELAXED, __HIP_MEMORY_SCOPE_AGENT);
}
__device__ inline uint4 rd16(const unsigned short* src) {
  const unsigned long long* s = (const unsigned long long*)src;
  unsigned long long a = __hip_atomic_load(s + 0, __ATOMIC_RELAXED, __HIP_MEMORY_SCOPE_AGENT);
  unsigned long long b = __hip_atomic_load(s + 1, __ATOMIC_RELAXED, __HIP_MEMORY_SCOPE_AGENT);
  union { unsigned long long q[2]; uint4 u; } x; x.q[0] = a; x.q[1] = b;
  return x.u;
}

// Intra-wave fences (rule #18: lgkmcnt asm needs a following sched_barrier).
__device__ inline void lds_fence() {
  asm volatile("s_waitcnt lgkmcnt(0)" ::: "memory");
  __builtin_amdgcn_sched_barrier(0);
}
__device__ inline void vm_drain() {
  asm volatile("s_waitcnt vmcnt(0)" ::: "memory");
  __builtin_amdgcn_sched_barrier(0);
}

// Poll 32 flag lines of this wave's plane (one per lane&31) until all >= seq.
__device__ inline void pollflags(const int* base, int lane, int seq) {
  const int* f = base + (size_t)(lane & 31) * 16;
  while (__any(__hip_atomic_load(f, __ATOMIC_RELAXED, __HIP_MEMORY_SCOPE_AGENT) < seq)) {}
  asm volatile("" ::: "memory");
  __builtin_amdgcn_sched_barrier(0);
}

// x-slab register reload: 12 scalar ushort loads (3 gates x 4 rows).
__device__ inline void xload(const unsigned short* __restrict__ xslab, size_t xb,
                             int t, unsigned short* uxr, unsigned short* uxz,
                             unsigned short* uxn) {
  const unsigned short* xp = xslab + (size_t)t * 32768 + xb;
#pragma unroll
  for (int r = 0; r < 4; ++r) {
    uxr[r] = xp[r * 512];
    uxz[r] = xp[33554432 + (size_t)r * 512];
    uxn[r] = xp[67108864 + (size_t)r * 512];
  }
}

// ---------------------------------------------------------------- prep
// wfrag layout per gate (262144 ushorts): idx = ((jt*16+kt)*64+lane)*8+i
// holds W[j=jt*16+(lane&15)][k=kt*32+(lane>>4)*8+i]  (MFMA B-fragment order)
__global__ void prep_kernel(const float* Wir, const float* Wiz, const float* Win,
                            const float* Whr, const float* Whz, const float* Whn,
                            unsigned short* wfrag, int* bar) {
  const float* Ws[6] = {Wir, Wiz, Win, Whr, Whz, Whn};
  int idx = blockIdx.x * 256 + threadIdx.x;
  if (idx < 6 * 262144) {
    int g = idx >> 18;
    int r = idx & 262143;
    int i = r & 7, lane = (r >> 3) & 63, kt = (r >> 9) & 15, jt = r >> 13;
    int n = lane & 15, q = lane >> 4;
    int j = jt * 16 + n, k = kt * 32 + q * 8 + i;
    wfrag[idx] = f2bf(Ws[g][j * 512 + k]);
  } else {
    int z = idx - 6 * 262144;
    if (z < 4096) bar[z] = 0;
  }
}

// ---------------------------------------------------------------- proj
// grid 8192: XCD-swizzled so the 8 j-tiles of one m-tile share an XCD (L2 reuse
// of the x A-tile).  Per WG: 64 (b,t)-rows x 64 j, K=512, 3 gates reuse A.
__global__ __launch_bounds__(256) void proj_kernel(const float* __restrict__ x,
                                                   const unsigned short* __restrict__ wfrag,
                                                   unsigned short* __restrict__ xslab) {
  __shared__ __align__(16) unsigned short As[64 * 520];
  int bid = blockIdx.x;
  int mLow = bid & 7, j8 = (bid >> 3) & 7, mHigh = bid >> 6;
  int mt = mHigh * 8 + mLow;            // 0..1023  (64-row tile of flattened b*T+t)
  int j0 = j8 * 64;
  int bb = mt >> 4, t0 = (mt & 15) << 6; // tile stays within one batch (T%64==0)
  const float* xbase = x + ((size_t)bb * 1024 + t0) * 512;
  for (int c = threadIdx.x; c < 64 * 128; c += 256) {
    int row = c >> 7, f4 = c & 127;
    float4 v = *((const float4*)(xbase + row * 512 + f4 * 4));
    ushort4 o;
    o.x = f2bf(v.x); o.y = f2bf(v.y); o.z = f2bf(v.z); o.w = f2bf(v.w);
    *((ushort4*)(As + row * 520 + f4 * 4)) = o;
  }
  __syncthreads();
  int lane = threadIdx.x & 63, w = threadIdx.x >> 6;
  int nn = lane & 15, qq = lane >> 4;
  for (int gate = 0; gate < 3; ++gate) {
    const unsigned short* wb = wfrag + (size_t)gate * 262144;
    f32x4 acc0 = {0.f,0.f,0.f,0.f}, acc1 = {0.f,0.f,0.f,0.f};
    f32x4 acc2 = {0.f,0.f,0.f,0.f}, acc3 = {0.f,0.f,0.f,0.f};
#pragma unroll
    for (int kt = 0; kt < 16; ++kt) {
      bf16x8 a = *((const bf16x8*)(As + (w * 16 + nn) * 520 + kt * 32 + qq * 8));
      uint4 b0 = *((const uint4*)(wb + (((size_t)(j8 * 4 + 0) * 16 + kt) * 64 + lane) * 8));
      uint4 b1 = *((const uint4*)(wb + (((size_t)(j8 * 4 + 1) * 16 + kt) * 64 + lane) * 8));
      uint4 b2 = *((const uint4*)(wb + (((size_t)(j8 * 4 + 2) * 16 + kt) * 64 + lane) * 8));
      uint4 b3 = *((const uint4*)(wb + (((size_t)(j8 * 4 + 3) * 16 + kt) * 64 + lane) * 8));
      acc0 = __builtin_amdgcn_mfma_f32_16x16x32_bf16(a, as_bf(b0), acc0, 0, 0, 0);
      acc1 = __builtin_amdgcn_mfma_f32_16x16x32_bf16(a, as_bf(b1), acc1, 0, 0, 0);
      acc2 = __builtin_amdgcn_mfma_f32_16x16x32_bf16(a, as_bf(b2), acc2, 0, 0, 0);
      acc3 = __builtin_amdgcn_mfma_f32_16x16x32_bf16(a, as_bf(b3), acc3, 0, 0, 0);
    }
    unsigned short* outs = xslab + (size_t)gate * 33554432;
    f32x4 accs[4] = {acc0, acc1, acc2, acc3};
#pragma unroll
    for (int jt = 0; jt < 4; ++jt) {
#pragma unroll
      for (int r = 0; r < 4; ++r) {
        int t = t0 + w * 16 + qq * 4 + r;
        int j = j0 + jt * 16 + nn;
        outs[(size_t)t * 32768 + bb * 512 + j] = f2bf(accs[jt][r]);
      }
    }
  }
}

// ---------------------------------------------------------------- scan
// WG g owns j in [g*16, g*16+16).  hfrag/rhfrag: [mt(4)][kt(16)][lane(64)][8]
// bf16 fragment order.  Wave w <-> plane w: touches only mt==w rows.
// Flags (bar): h set = lines [0..128) at bar[(w*32+g)*16], rh set = lines
// [128..256) at bar[2048 + (w*32+g)*16].  Seq: h of step t = t+1, rh = t+1.
__global__ __launch_bounds__(256) void scan_kernel(
    const unsigned short* __restrict__ wfragH, const unsigned short* __restrict__ xslab,
    const float* __restrict__ h0, const float* __restrict__ bhr,
    const float* __restrict__ bhz, const float* __restrict__ bhn,
    float* __restrict__ out, unsigned short* hfrag, unsigned short* rhfrag, int* bar) {
  __shared__ __align__(16) unsigned short whf[3 * 8192];   // 48 KB weight slices
  __shared__ __align__(16) unsigned short stg[4 * 256];    // per-wave 16x16 staging
  const int g = blockIdx.x, tid = threadIdx.x;
  const int lane = tid & 63, w = tid >> 6;
  const int nn = lane & 15, qq = lane >> 4;

  // weight slices: jt == g is a contiguous 8192-ushort run per gate
  for (int c = tid; c < 3 * 1024; c += 256) {
    int gate = c >> 10, chunk = c & 1023;
    *((uint4*)(whf + gate * 8192 + chunk * 8)) =
        *((const uint4*)(wfragH + (size_t)gate * 262144 + (size_t)g * 8192 + chunk * 8));
  }

  // per-thread fp32 h state: rows b = w*16+qq*4+r, col g*16+nn
  float hreg[4];
#pragma unroll
  for (int r = 0; r < 4; ++r)
    hreg[r] = h0[(w * 16 + qq * 4 + r) * 512 + g * 16 + nn];

  const float br = bhr[g * 16 + nn], bz = bhz[g * 16 + nn], bn = bhn[g * 16 + nn];

  // publish addressing: lane l<32 owns chunk (row=l>>1, q=l&1) of plane w
  const int prow = lane >> 1, pq = lane & 1;
  const int ktg = g >> 1, qg = ((g & 1) << 1) | pq;
  const int plg = prow | (qg << 4);
  const size_t pdst = ((size_t)(w * 16 + ktg) * 64 + plg) * 8;

  // init this plane-slice of hfrag from h_0, seq 1
  if (lane < 32) {
    int b = w * 16 + prow, k0 = g * 16 + pq * 8;
    float4 v0 = *((const float4*)(h0 + b * 512 + k0));
    float4 v1 = *((const float4*)(h0 + b * 512 + k0 + 4));
    union { unsigned short s[8]; uint4 v; } u;
    u.s[0] = f2bf(v0.x); u.s[1] = f2bf(v0.y); u.s[2] = f2bf(v0.z); u.s[3] = f2bf(v0.w);
    u.s[4] = f2bf(v1.x); u.s[5] = f2bf(v1.y); u.s[6] = f2bf(v1.z); u.s[7] = f2bf(v1.w);
    pub16(hfrag + pdst, u.v);
  }
  vm_drain();
  if (lane == 0)
    __hip_atomic_store(bar + (w * 32 + g) * 16, 1, __ATOMIC_RELAXED, __HIP_MEMORY_SCOPE_AGENT);

  // x register prefetch for t=0
  const size_t xb = (size_t)(w * 16 + qq * 4) * 512 + g * 16 + nn;
  unsigned short uxr[4], uxz[4], uxn[4];
  xload(xslab, xb, 0, uxr, uxz, uxn);

  __syncthreads();   // whf ready (only barrier in the kernel)

  int* const hfl  = bar + w * 512;           // 32 lines of this plane
  int* const rhfl = bar + 2048 + w * 512;
  int* const myh  = bar + (w * 32 + g) * 16;
  int* const myrh = bar + 2048 + (w * 32 + g) * 16;
  unsigned short* const stgw = stg + w * 256;

  for (int t = 0; t < 1024; ++t) {
    // ---- phase 1: wait h(t), compute r,z, publish r*h
    pollflags(hfl, lane, t + 1);
    uint4 af[16];
#pragma unroll
    for (int kt = 0; kt < 16; ++kt)
      af[kt] = rd16(hfrag + ((size_t)(w * 16 + kt) * 64 + lane) * 8);
    f32x4 ar = {0.f,0.f,0.f,0.f}, az = {0.f,0.f,0.f,0.f};
#pragma unroll
    for (int kt = 0; kt < 16; ++kt) {
      bf16x8 a = as_bf(af[kt]);
      bf16x8 b0 = *((const bf16x8*)(whf + 0 * 8192 + (kt * 64 + lane) * 8));
      bf16x8 b1 = *((const bf16x8*)(whf + 1 * 8192 + (kt * 64 + lane) * 8));
      ar = __builtin_amdgcn_mfma_f32_16x16x32_bf16(a, b0, ar, 0, 0, 0);
      az = __builtin_amdgcn_mfma_f32_16x16x32_bf16(a, b1, az, 0, 0, 0);
    }
    float zv[4];
#pragma unroll
    for (int r = 0; r < 4; ++r) {
      float rv = sigm(ar[r] + bf2f(uxr[r]) + br);
      zv[r] = sigm(az[r] + bf2f(uxz[r]) + bz);
      stgw[(qq * 4 + r) * 16 + nn] = f2bf(rv * hreg[r]);
    }
    lds_fence();
    if (lane < 32)
      pub16(rhfrag + pdst, *((const uint4*)(stgw + prow * 16 + pq * 8)));
    vm_drain();
    if (lane == 0)
      __hip_atomic_store(myrh, t + 1, __ATOMIC_RELAXED, __HIP_MEMORY_SCOPE_AGENT);

    // ---- phase 2: wait r*h(t), compute n + h_new, publish h(t+1)
    pollflags(rhfl, lane, t + 1);
#pragma unroll
    for (int kt = 0; kt < 16; ++kt)
      af[kt] = rd16(rhfrag + ((size_t)(w * 16 + kt) * 64 + lane) * 8);
    f32x4 an = {0.f,0.f,0.f,0.f};
#pragma unroll
    for (int kt = 0; kt < 16; ++kt) {
      bf16x8 a = as_bf(af[kt]);
      bf16x8 b2 = *((const bf16x8*)(whf + 2 * 8192 + (kt * 64 + lane) * 8));
      an = __builtin_amdgcn_mfma_f32_16x16x32_bf16(a, b2, an, 0, 0, 0);
    }
    float hv[4];
#pragma unroll
    for (int r = 0; r < 4; ++r) {
      float nv = tanhfast(an[r] + bf2f(uxn[r]) + bn);
      float hn = (1.f - zv[r]) * hreg[r] + zv[r] * nv;
      hreg[r] = hn;
      hv[r] = hn;
      stgw[(qq * 4 + r) * 16 + nn] = f2bf(hn);
    }
    lds_fence();
    if (lane < 32)
      pub16(hfrag + pdst, *((const uint4*)(stgw + prow * 16 + pq * 8)));
    vm_drain();
    if (lane == 0)
      __hip_atomic_store(myh, t + 2, __ATOMIC_RELAXED, __HIP_MEMORY_SCOPE_AGENT);

    // ---- poll shadow: HBM out-stores + next-step x register loads
#pragma unroll
    for (int r = 0; r < 4; ++r) {
      int b = w * 16 + qq * 4 + r;
      out[((size_t)b * 1024 + t) * 512 + g * 16 + nn] = hv[r];
      if (t == 1023) out[(size_t)33554432 + b * 512 + g * 16 + nn] = hv[r];
    }
    if (t < 1023) xload(xslab, xb, t + 1, uxr, uxz, uxn);
  }
}

// ---------------------------------------------------------------- launch
extern "C" void kernel_launch(void* const* d_in, const int* in_sizes, int n_in,
                              void* d_out, int out_size, void* d_ws, size_t ws_size,
                              hipStream_t stream) {
  (void)in_sizes; (void)n_in; (void)out_size; (void)ws_size;
  const float* x   = (const float*)d_in[0];
  const float* h0  = (const float*)d_in[1];
  const float* Wir = (const float*)d_in[2];
  const float* Wiz = (const float*)d_in[3];
  const float* Win = (const float*)d_in[4];
  const float* Whr = (const float*)d_in[5];
  const float* Whz = (const float*)d_in[6];
  const float* Whn = (const float*)d_in[7];
  const float* bhr = (const float*)d_in[8];
  const float* bhz = (const float*)d_in[9];
  const float* bhn = (const float*)d_in[10];
  float* out = (float*)d_out;
  char* w = (char*)d_ws;
  // ws layout (bytes):
  //   wfrag   @ 0           : 6*262144*2 = 3,145,728
  //   xslab   @ 3,145,728   : 3*33,554,432*2 = 201,326,592
  //   hfrag   @ 204,472,320 : 65,536
  //   rhfrag  @ 204,537,856 : 65,536
  //   bar     @ 204,603,392 : 16,384            (total ~195.2 MiB)
  unsigned short* wfrag  = (unsigned short*)w;
  unsigned short* xslab  = (unsigned short*)(w + 3145728);
  unsigned short* hfrag  = (unsigned short*)(w + 204472320);
  unsigned short* rhfrag = (unsigned short*)(w + 204537856);
  int* bar = (int*)(w + 204603392);

  hipLaunchKernelGGL(prep_kernel, dim3(6160), dim3(256), 0, stream,
                     Wir, Wiz, Win, Whr, Whz, Whn, wfrag, bar);
  hipLaunchKernelGGL(proj_kernel, dim3(8192), dim3(256), 0, stream,
                     x, wfrag, xslab);
  hipLaunchKernelGGL(scan_kernel, dim3(NWG), dim3(256), 0, stream,
                     wfrag + (size_t)3 * 262144, xslab, h0, bhr, bhz, bhn,
                     out, hfrag, rhfrag, bar);
}